// Round 10
// baseline (47.536 us; speedup 1.0000x reference)
//
#include <hip/hip_runtime.h>
#include <math.h>

#define NVOX (2 * 128 * 128 * 128)   // 4,194,304
#define KS 13
#define KR 6
#define LROWS 44                      // 32 output rows + 2*6 halo

__device__ __forceinline__ float4 LD4(const float* p) {
    return *reinterpret_cast<const float4*>(p);
}

// Per-thread normalized Gaussian weights (sigma = clip(scale, 0.1, 10)).
__device__ __forceinline__ void make_weights(float scale, float* wv) {
    float sig = fminf(fmaxf(scale, 0.1f), 10.0f);
    float inv2s2 = -1.0f / (2.0f * sig * sig);
    float sum = 0.f;
#pragma unroll
    for (int t = 0; t < KS; ++t) {
        float d = (float)(t - KR);
        wv[t] = __expf(d * d * inv2s2);
        sum += wv[t];
    }
    float r = 1.0f / sum;
#pragma unroll
    for (int t = 0; t < KS; ++t) wv[t] *= r;
}

__device__ __forceinline__ int CH(int v) {
    return v < 0 ? 0 : (v > 127 ? 127 : v);
}

__device__ __forceinline__ void lohi(int c, int& lo, int& hi, float& s) {
    lo = c > 0 ? c - 1 : 0;
    hi = c < 127 ? c + 1 : 127;
    s = 1.0f / (float)(hi - lo);
}

// ---------------------------------------------------------------------------
// 1) Fused W+H blur, 4 blocks per (b,d) slice (h-quarters + 6-row halo).
//    Phase A: 8 w-outputs per slot, all-vector loads. XCD swizzle (nwg=1024).
// ---------------------------------------------------------------------------
__global__ __launch_bounds__(256) void wh_blur_kernel(const float* __restrict__ in,
                                                      float* __restrict__ out,
                                                      const float* __restrict__ scale_p) {
    __shared__ float T[LROWS * 128];      // 22.5 KB
    const int i = blockIdx.x;
    const int wid = ((i & 7) << 7) | (i >> 3);   // bijective, nwg=1024
    const int slice = wid >> 2;           // b*128 + d
    const int h0 = (wid & 3) << 5;        // 0/32/64/96
    const float* sp = in + (slice << 14);
    float* op = out + (slice << 14);

    float wv[KS];
    make_weights(scale_p[0], wv);

    // ---- Phase A: W-blur rows h0-6 .. h0+37 (clamped) into T[0..43] ----
    for (int it = 0; it < 3; ++it) {
        int g = threadIdx.x + (it << 8);
        if (g < LROWS * 16) {
            int wseg = g & 15;
            int w0 = wseg << 3;
            int lr = g >> 4;
            int r = h0 - 6 + lr;
            r = r < 0 ? 0 : (r > 127 ? 127 : r);
            const float* rp = sp + (r << 7);

            float F[24];                  // F[i] = row[w0-8+i]; taps F[k+2..k+14]
            if (wseg >= 1 && wseg <= 14) {
#pragma unroll
                for (int i2 = 0; i2 < 6; ++i2) {
                    float4 q = LD4(rp + w0 - 8 + (i2 << 2));
                    F[4 * i2] = q.x; F[4 * i2 + 1] = q.y;
                    F[4 * i2 + 2] = q.z; F[4 * i2 + 3] = q.w;
                }
            } else if (wseg == 0) {       // w0 = 0: F[0..7] clamp to rp[0]
                float e = rp[0];
#pragma unroll
                for (int i2 = 0; i2 < 8; ++i2) F[i2] = e;
#pragma unroll
                for (int i2 = 0; i2 < 4; ++i2) {
                    float4 q = LD4(rp + (i2 << 2));
                    F[8 + 4 * i2] = q.x; F[9 + 4 * i2] = q.y;
                    F[10 + 4 * i2] = q.z; F[11 + 4 * i2] = q.w;
                }
            } else {                      // wseg = 15, w0 = 120: F[16..23] clamp
                float e = rp[127];
#pragma unroll
                for (int i2 = 0; i2 < 4; ++i2) {
                    float4 q = LD4(rp + 112 + (i2 << 2));
                    F[4 * i2] = q.x; F[4 * i2 + 1] = q.y;
                    F[4 * i2 + 2] = q.z; F[4 * i2 + 3] = q.w;
                }
#pragma unroll
                for (int i2 = 16; i2 < 24; ++i2) F[i2] = e;
            }

            float a[8];
#pragma unroll
            for (int k = 0; k < 8; ++k) a[k] = 0.f;
#pragma unroll
            for (int t = 0; t < KS; ++t) {
                float wt = wv[t];
#pragma unroll
                for (int k = 0; k < 8; ++k) a[k] = fmaf(wt, F[k + 2 + t], a[k]);
            }
            *reinterpret_cast<float4*>(&T[(lr << 7) + w0]) =
                make_float4(a[0], a[1], a[2], a[3]);
            *reinterpret_cast<float4*>(&T[(lr << 7) + w0 + 4]) =
                make_float4(a[4], a[5], a[6], a[7]);
        }
    }
    __syncthreads();

    // ---- Phase B: H-blur 32 output rows (8 strips of 4 rows) ----
    {
        const int w0 = (threadIdx.x & 31) << 2;
        const int r0 = (threadIdx.x >> 5) << 2;

        float4 win[KS];
#pragma unroll
        for (int t = 0; t < KS; ++t) win[t] = LD4(&T[((r0 + t) << 7) + w0]);
#pragma unroll
        for (int s = 0; s < 4; ++s) {
            float4 acc = make_float4(0.f, 0.f, 0.f, 0.f);
#pragma unroll
            for (int t = 0; t < KS; ++t) {
                float4 v = win[(s + t) % KS];
                float wt = wv[t];
                acc.x = fmaf(wt, v.x, acc.x);
                acc.y = fmaf(wt, v.y, acc.y);
                acc.z = fmaf(wt, v.z, acc.z);
                acc.w = fmaf(wt, v.w, acc.w);
            }
            *reinterpret_cast<float4*>(op + ((h0 + r0 + s) << 7) + w0) = acc;
            int nl = r0 + s + 13;
            nl = nl > LROWS - 1 ? LROWS - 1 : nl;
            win[s % KS] = LD4(&T[(nl << 7) + w0]);
        }
    }
}

// ---------------------------------------------------------------------------
// 2) FUSED D-blur + Hessian + MLP.
//    Block = (b, d0 chunk of 4, hb chunk of 8, full w). 1024 blocks.
//    Fill: 384 (row,wseg) columns compute S-tile [8 planes][12 rows][128 w]
//    from ws1 via rolling 20-plane window (static win[p+t]; clamped-dead
//    planes/rows never read -> no boundary branches). 48 KB LDS.
//    Hess: all stencil operands read from LDS (clamped indices replace the
//    shuffle + edge-select machinery; expressions verbatim -> bit-identical).
// ---------------------------------------------------------------------------
__global__ __launch_bounds__(256) void dhess_kernel(const float* __restrict__ ws1,
                                const float* __restrict__ scale_p,
                                const float* __restrict__ W1, const float* __restrict__ b1,
                                const float* __restrict__ W2, const float* __restrict__ b2,
                                float* __restrict__ out) {
    __shared__ float S[8][12][128];              // 48 KB
    const int i = blockIdx.x;
    const int wid = ((i & 7) << 7) | (i >> 3);   // bijective, nwg=1024
    const int b  = wid >> 9;
    const int d0 = ((wid >> 4) & 31) << 2;       // 0,4,...,124
    const int hb = (wid & 15) << 3;              // 0,8,...,120

    float wv[KS];
    make_weights(scale_p[0], wv);
    const float* wbase = ws1 + (b << 21);

    // ---- Fill phase: S-tile from ws1 ----
    for (int it = 0; it < 2; ++it) {
        int col = (it << 8) + threadIdx.x;       // 0..511, valid < 384
        if (col < 384) {
            int r = col >> 5;                    // 0..11
            int w0 = (col & 31) << 2;
            int gr = CH(hb - 2 + r);
            const float* cb = wbase + (gr << 7) + w0;
            float4 win[20];                      // ws1 planes d0-8..d0+11 (clamped)
#pragma unroll
            for (int k = 0; k < 20; ++k) {
                int g = d0 - 8 + k;
                g = g < 0 ? 0 : (g > 127 ? 127 : g);
                win[k] = LD4(cb + (g << 14));
            }
#pragma unroll
            for (int p = 0; p < 8; ++p) {
                float4 acc = make_float4(0.f, 0.f, 0.f, 0.f);
#pragma unroll
                for (int t = 0; t < KS; ++t) {
                    float4 v = win[p + t];
                    float wt = wv[t];
                    acc.x = fmaf(wt, v.x, acc.x);
                    acc.y = fmaf(wt, v.y, acc.y);
                    acc.z = fmaf(wt, v.z, acc.z);
                    acc.w = fmaf(wt, v.w, acc.w);
                }
                *reinterpret_cast<float4*>(&S[p][r][w0]) = acc;
            }
        }
    }
    __syncthreads();

    // ---- Hess + MLP phase ----
    const int l  = threadIdx.x & 31;
    const int hj = threadIdx.x >> 5;             // 0..7
    const int w0 = l << 2;
    const int h  = hb + hj;
    const bool l0 = (l == 0), l31 = (l == 31);

    int ti, tj;
    int lh, hh; float sh; lohi(h, lh, hh, sh);
    float s_hh, s_lh; lohi(hh, ti, tj, s_hh); lohi(lh, ti, tj, s_lh);
    const bool h_top = (h == 127), h_bot = (h == 0);

    float sw[4], s_hw[4], s_lw[4];
#pragma unroll
    for (int j = 0; j < 4; ++j) {
        int lw, hw; lohi(w0 + j, lw, hw, sw[j]);
        lohi(hw, ti, tj, s_hw[j]); lohi(lw, ti, tj, s_lw[j]);
    }

    const float scale = scale_p[0];
    float b1e[10];
#pragma unroll
    for (int u = 0; u < 10; ++u) b1e[u] = fmaf(scale, W1[u * 7 + 6], b1[u]);
    const float b2s = b2[0];

    // Local row indices (tile row = global CH(row) - (hb-2))
    const int lr0  = hj + 2;
    const int lrm1 = CH(h - 1) - hb + 2;
    const int lrm2 = CH(h - 2) - hb + 2;
    const int lrp1 = CH(h + 1) - hb + 2;
    const int lrp2 = CH(h + 2) - hb + 2;

    // Clamped w indices for edge scalars
    const int wm2 = CH(w0 - 2), wm1 = CH(w0 - 1);
    const int wp4 = CH(w0 + 4), wp5 = CH(w0 + 5);

    float* obase = out + (b << 21) + (h << 7) + w0;

#pragma unroll
    for (int dj = 0; dj < 4; ++dj) {
        const int d = d0 + dj;
        int ld, hd; float sd; lohi(d, ld, hd, sd);
        float s_hd, s_ld; lohi(hd, ti, tj, s_hd); lohi(ld, ti, tj, s_ld);
        const bool d_top = (d == 127), d_bot = (d == 0);
        const int lpd   = dj + 2;
        const int lpld  = ld - d0 + 2;
        const int lphd  = hd - d0 + 2;
        const int lpdp2 = CH(d + 2) - d0 + 2;
        const int lpdm2 = CH(d - 2) - d0 + 2;

        // --- Gather operands from LDS ---
        const float* rv = &S[lpd][lr0][0];
        float4 vq = LD4(&rv[w0]);
        const float va8[8] = {rv[wm2], rv[wm1], vq.x, vq.y, vq.z, vq.w, rv[wp4], rv[wp5]};

        const float* rn1 = &S[lpd][lrm1][0];
        float4 n1q = LD4(&rn1[w0]);
        const float n1_6[6] = {rn1[wm1], n1q.x, n1q.y, n1q.z, n1q.w, rn1[wp4]};

        const float* rn3 = &S[lpd][lrp1][0];
        float4 n3q = LD4(&rn3[w0]);
        const float n3_6[6] = {rn3[wm1], n3q.x, n3q.y, n3q.z, n3q.w, rn3[wp4]};

        const float* rpm = &S[lpld][lr0][0];
        float4 pm1q = LD4(&rpm[w0]);
        const float pm1_6[6] = {rpm[wm1], pm1q.x, pm1q.y, pm1q.z, pm1q.w, rpm[wp4]};

        const float* rpp = &S[lphd][lr0][0];
        float4 pp1q = LD4(&rpp[w0]);
        const float pp1_6[6] = {rpp[wm1], pp1q.x, pp1q.y, pp1q.z, pp1q.w, rpp[wp4]};

        float4 n0q  = LD4(&S[lpd][lrm2][w0]);
        float4 n4q  = LD4(&S[lpd][lrp2][w0]);
        float4 pm0q = LD4(&S[lpld][lrm1][w0]);
        float4 pm2q = LD4(&S[lpld][lrp1][w0]);
        float4 pp0q = LD4(&S[lphd][lrm1][w0]);
        float4 pp2q = LD4(&S[lphd][lrp1][w0]);
        float4 qpq  = LD4(&S[lpdp2][lr0][w0]);
        float4 qmq  = LD4(&S[lpdm2][lr0][w0]);

        const float n0f[4]  = {n0q.x, n0q.y, n0q.z, n0q.w};
        const float n4f[4]  = {n4q.x, n4q.y, n4q.z, n4q.w};
        const float pm0f[4] = {pm0q.x, pm0q.y, pm0q.z, pm0q.w};
        const float pm2f[4] = {pm2q.x, pm2q.y, pm2q.z, pm2q.w};
        const float pp0f[4] = {pp0q.x, pp0q.y, pp0q.z, pp0q.w};
        const float pp2f[4] = {pp2q.x, pp2q.y, pp2q.z, pp2q.w};
        const float qpf[4]  = {qpq.x, qpq.y, qpq.z, qpq.w};
        const float qmf[4]  = {qmq.x, qmq.y, qmq.z, qmq.w};

        float ov[4];
#pragma unroll
        for (int j = 0; j < 4; ++j) {
            const float fDD = sd * (s_hd * (qpf[j] - (d_top ? pm1_6[j + 1] : va8[j + 2]))
                                  - s_ld * ((d_bot ? pp1_6[j + 1] : va8[j + 2]) - qmf[j]));
            const float fHH = sh * (s_hh * (n4f[j] - (h_top ? n1_6[j + 1] : va8[j + 2]))
                                  - s_lh * ((h_bot ? n3_6[j + 1] : va8[j + 2]) - n0f[j]));
            const float fDH = sd * sh * ((pp2f[j] - pp0f[j]) - (pm2f[j] - pm0f[j]));
            const float fHW = sh * sw[j] * ((n3_6[j + 2] - n3_6[j]) - (n1_6[j + 2] - n1_6[j]));
            const float fDW = sd * sw[j] * ((pp1_6[j + 2] - pp1_6[j]) - (pm1_6[j + 2] - pm1_6[j]));
            const float Aw = (j == 3 && l31) ? va8[j + 1] : va8[j + 2];
            const float Bw = (j == 0 && l0) ? va8[j + 3] : va8[j + 2];
            const float fWW = sw[j] * (s_hw[j] * (va8[j + 4] - Aw) - s_lw[j] * (Bw - va8[j]));

            const float ft[6] = {fDD, fDH, fDW, fHH, fHW, fWW};
            float o = b2s;
#pragma unroll
            for (int u = 0; u < 10; ++u) {
                float a = b1e[u];
#pragma unroll
                for (int k = 0; k < 6; ++k) a = fmaf(ft[k], W1[u * 7 + k], a);
                a = fmaxf(a, 0.f);
                o = fmaf(a, W2[u], o);
            }
            float e = __expf(-o);
            ov[j] = __builtin_amdgcn_rcpf(1.0f + e);
        }
        *reinterpret_cast<float4*>(obase + (d << 14)) = make_float4(ov[0], ov[1], ov[2], ov[3]);
    }
}

// ---------------------------------------------------------------------------
extern "C" void kernel_launch(void* const* d_in, const int* in_sizes, int n_in,
                              void* d_out, int out_size, void* d_ws, size_t ws_size,
                              hipStream_t stream) {
    const float* x     = (const float*)d_in[0];
    const float* scale = (const float*)d_in[1];
    const float* W1    = (const float*)d_in[2];
    const float* b1    = (const float*)d_in[3];
    const float* W2    = (const float*)d_in[4];
    const float* b2    = (const float*)d_in[5];
    float* out = (float*)d_out;

    float* ws1 = (float*)d_ws;            // W+H-blurred volume (16 MB)

    wh_blur_kernel<<<2 * 128 * 4, 256, 0, stream>>>(x, ws1, scale);          // W+H
    dhess_kernel<<<2 * 32 * 16, 256, 0, stream>>>(ws1, scale, W1, b1, W2, b2, out);
}

// Round 11
// 45.051 us; speedup vs baseline: 1.0552x; 1.0552x over previous
//
#include <hip/hip_runtime.h>
#include <math.h>

#define NVOX (2 * 128 * 128 * 128)   // 4,194,304
#define KS 13
#define KR 6
#define LROWS 44                      // 32 output rows + 2*6 halo

__device__ __forceinline__ float4 LD4(const float* p) {
    return *reinterpret_cast<const float4*>(p);
}

// Per-thread normalized Gaussian weights (sigma = clip(scale, 0.1, 10)).
__device__ __forceinline__ void make_weights(float scale, float* wv) {
    float sig = fminf(fmaxf(scale, 0.1f), 10.0f);
    float inv2s2 = -1.0f / (2.0f * sig * sig);
    float sum = 0.f;
#pragma unroll
    for (int t = 0; t < KS; ++t) {
        float d = (float)(t - KR);
        wv[t] = __expf(d * d * inv2s2);
        sum += wv[t];
    }
    float r = 1.0f / sum;
#pragma unroll
    for (int t = 0; t < KS; ++t) wv[t] *= r;
}

__device__ __forceinline__ int CH(int v) {
    return v < 0 ? 0 : (v > 127 ? 127 : v);
}

__device__ __forceinline__ void lohi(int c, int& lo, int& hi, float& s) {
    lo = c > 0 ? c - 1 : 0;
    hi = c < 127 ? c + 1 : 127;
    s = 1.0f / (float)(hi - lo);
}

// ---------------------------------------------------------------------------
// 1) Fused W+H blur, 4 blocks per (b,d) slice (h-quarters + 6-row halo).
//    Phase A: 8 w-outputs per slot, all-vector loads. XCD swizzle (nwg=1024).
// ---------------------------------------------------------------------------
__global__ __launch_bounds__(256) void wh_blur_kernel(const float* __restrict__ in,
                                                      float* __restrict__ out,
                                                      const float* __restrict__ scale_p) {
    __shared__ float T[LROWS * 128];      // 22.5 KB
    const int i = blockIdx.x;
    const int wid = ((i & 7) << 7) | (i >> 3);   // bijective, nwg=1024
    const int slice = wid >> 2;           // b*128 + d
    const int h0 = (wid & 3) << 5;        // 0/32/64/96
    const float* sp = in + (slice << 14);
    float* op = out + (slice << 14);

    float wv[KS];
    make_weights(scale_p[0], wv);

    // ---- Phase A: W-blur rows h0-6 .. h0+37 (clamped) into T[0..43] ----
    for (int it = 0; it < 3; ++it) {
        int g = threadIdx.x + (it << 8);
        if (g < LROWS * 16) {
            int wseg = g & 15;
            int w0 = wseg << 3;
            int lr = g >> 4;
            int r = h0 - 6 + lr;
            r = r < 0 ? 0 : (r > 127 ? 127 : r);
            const float* rp = sp + (r << 7);

            float F[24];                  // F[i] = row[w0-8+i]; taps F[k+2..k+14]
            if (wseg >= 1 && wseg <= 14) {
#pragma unroll
                for (int i2 = 0; i2 < 6; ++i2) {
                    float4 q = LD4(rp + w0 - 8 + (i2 << 2));
                    F[4 * i2] = q.x; F[4 * i2 + 1] = q.y;
                    F[4 * i2 + 2] = q.z; F[4 * i2 + 3] = q.w;
                }
            } else if (wseg == 0) {       // w0 = 0: F[0..7] clamp to rp[0]
                float e = rp[0];
#pragma unroll
                for (int i2 = 0; i2 < 8; ++i2) F[i2] = e;
#pragma unroll
                for (int i2 = 0; i2 < 4; ++i2) {
                    float4 q = LD4(rp + (i2 << 2));
                    F[8 + 4 * i2] = q.x; F[9 + 4 * i2] = q.y;
                    F[10 + 4 * i2] = q.z; F[11 + 4 * i2] = q.w;
                }
            } else {                      // wseg = 15, w0 = 120: F[16..23] clamp
                float e = rp[127];
#pragma unroll
                for (int i2 = 0; i2 < 4; ++i2) {
                    float4 q = LD4(rp + 112 + (i2 << 2));
                    F[4 * i2] = q.x; F[4 * i2 + 1] = q.y;
                    F[4 * i2 + 2] = q.z; F[4 * i2 + 3] = q.w;
                }
#pragma unroll
                for (int i2 = 16; i2 < 24; ++i2) F[i2] = e;
            }

            float a[8];
#pragma unroll
            for (int k = 0; k < 8; ++k) a[k] = 0.f;
#pragma unroll
            for (int t = 0; t < KS; ++t) {
                float wt = wv[t];
#pragma unroll
                for (int k = 0; k < 8; ++k) a[k] = fmaf(wt, F[k + 2 + t], a[k]);
            }
            *reinterpret_cast<float4*>(&T[(lr << 7) + w0]) =
                make_float4(a[0], a[1], a[2], a[3]);
            *reinterpret_cast<float4*>(&T[(lr << 7) + w0 + 4]) =
                make_float4(a[4], a[5], a[6], a[7]);
        }
    }
    __syncthreads();

    // ---- Phase B: H-blur 32 output rows (8 strips of 4 rows) ----
    {
        const int w0 = (threadIdx.x & 31) << 2;
        const int r0 = (threadIdx.x >> 5) << 2;

        float4 win[KS];
#pragma unroll
        for (int t = 0; t < KS; ++t) win[t] = LD4(&T[((r0 + t) << 7) + w0]);
#pragma unroll
        for (int s = 0; s < 4; ++s) {
            float4 acc = make_float4(0.f, 0.f, 0.f, 0.f);
#pragma unroll
            for (int t = 0; t < KS; ++t) {
                float4 v = win[(s + t) % KS];
                float wt = wv[t];
                acc.x = fmaf(wt, v.x, acc.x);
                acc.y = fmaf(wt, v.y, acc.y);
                acc.z = fmaf(wt, v.z, acc.z);
                acc.w = fmaf(wt, v.w, acc.w);
            }
            *reinterpret_cast<float4*>(op + ((h0 + r0 + s) << 7) + w0) = acc;
            int nl = r0 + s + 13;
            nl = nl > LROWS - 1 ? LROWS - 1 : nl;
            win[s % KS] = LD4(&T[(nl << 7) + w0]);
        }
    }
}

// ---------------------------------------------------------------------------
// 2) D-blur, cooperative LDS staging. Block = (b, h, d-half of 64).
//    Stage 76 planes x 128 w into 38.9 KB LDS (2432 coalesced float4,
//    ~9.5/thread, all independent -> one latency per block). Each thread
//    then register-loads its 20-plane sub-window from LDS and computes 8
//    outputs with static indices. Global amplification 2.5x -> 1.19x;
//    4 blocks/CU. Tap order verbatim -> bit-identical. 512 blocks.
// ---------------------------------------------------------------------------
__global__ __launch_bounds__(256) void dblur_kernel(const float* __restrict__ in,
                                                    float* __restrict__ out,
                                                    const float* __restrict__ scale_p) {
    __shared__ float P[76][128];                 // 38.9 KB
    const int i = blockIdx.x;
    const int wid = ((i & 7) << 6) | (i >> 3);   // bijective, nwg=512
    const int b     = wid >> 8;
    const int dhalf = (wid >> 7) & 1;
    const int h     = wid & 127;
    const int d0    = dhalf << 6;                // 0 or 64
    const int tid   = threadIdx.x;

    float wv[KS];
    make_weights(scale_p[0], wv);

    // ---- Stage planes d0-6 .. d0+69 (clamped), full w, into LDS ----
    const float* rbase = in + (b << 21) + (h << 7);
#pragma unroll
    for (int k = 0; k < 10; ++k) {
        int idx = (k << 8) + tid;                // 0..2559, valid < 2432
        if (idx < 76 * 32) {
            int p = idx >> 5;
            int c = (idx & 31) << 2;
            int g = CH(d0 - 6 + p);
            *reinterpret_cast<float4*>(&P[p][c]) = LD4(rbase + (g << 14) + c);
        }
    }
    __syncthreads();

    // ---- Compute: thread = (dg 0..7, lane 0..31); 8 outputs each ----
    const int dg = tid >> 5;
    const int w0 = (tid & 31) << 2;
    float* obase = out + (b << 21) + (h << 7) + w0;

    float4 wreg[20];                             // staged idx dg*8 .. dg*8+19
#pragma unroll
    for (int t = 0; t < 20; ++t) wreg[t] = LD4(&P[(dg << 3) + t][w0]);

#pragma unroll
    for (int s = 0; s < 8; ++s) {
        float4 acc = make_float4(0.f, 0.f, 0.f, 0.f);
#pragma unroll
        for (int t = 0; t < KS; ++t) {
            float4 v = wreg[s + t];              // static index after unroll
            float wt = wv[t];
            acc.x = fmaf(wt, v.x, acc.x);
            acc.y = fmaf(wt, v.y, acc.y);
            acc.z = fmaf(wt, v.z, acc.z);
            acc.w = fmaf(wt, v.w, acc.w);
        }
        *reinterpret_cast<float4*>(obase + ((d0 + (dg << 3) + s) << 14)) = acc;
    }
}

// ---------------------------------------------------------------------------
// 3) Hessian + MLP, h-sliding register window + shuffle w-neighbors,
//    h-chunk of 4 (1024 blocks). scale folded into b1 (launch-constant).
//    XCD swizzle (nwg=1024). (R5/R9 version - local optimum.)
// ---------------------------------------------------------------------------
__global__ __launch_bounds__(256) void hess_mlp_kernel(const float* __restrict__ S,
                                const float* __restrict__ scale_p,
                                const float* __restrict__ W1, const float* __restrict__ b1,
                                const float* __restrict__ W2, const float* __restrict__ b2,
                                float* __restrict__ out) {
    const int i = blockIdx.x;
    const int wid = ((i & 7) << 7) | (i >> 3);   // bijective, nwg=1024
    const int t = wid * 256 + threadIdx.x;       // 0..262143
    const int l = t & 31;
    const int w0 = l << 2;
    const int hb = ((t >> 5) & 31) << 2;         // h-strip base (4 rows)
    const int d = (t >> 10) & 127;
    const int b = t >> 17;
    const int lane = threadIdx.x & 63;
    const bool l0 = (l == 0), l31 = (l == 31);

    int ld, hd; float sd; lohi(d, ld, hd, sd);
    int ti, tj; float s_hd, s_ld;
    lohi(hd, ti, tj, s_hd); lohi(ld, ti, tj, s_ld);
    const bool d_top = (d == 127), d_bot = (d == 0);
    const int dp2 = d > 125 ? 127 : d + 2;
    const int dm2 = d < 2 ? 0 : d - 2;

    float sw[4], s_hw[4], s_lw[4];
#pragma unroll
    for (int j = 0; j < 4; ++j) {
        int lw, hw; lohi(w0 + j, lw, hw, sw[j]);
        lohi(hw, ti, tj, s_hw[j]); lohi(lw, ti, tj, s_lw[j]);
    }

    const float scale = scale_p[0];
    // Fold the constant 7th feature (scale) into the bias: saves 10 FMA/voxel.
    float b1e[10];
#pragma unroll
    for (int u = 0; u < 10; ++u) b1e[u] = fmaf(scale, W1[u * 7 + 6], b1[u]);

    const float* base = S + (b << 21) + w0;
    auto RP = [&](int dd, int hh) { return base + (dd << 14) + (hh << 7); };
    float* obase = out + (b << 21) + (d << 14) + w0;

    float4 nd0 = LD4(RP(d, CH(hb - 2))), nd1 = LD4(RP(d, CH(hb - 1))),
           nd2 = LD4(RP(d, hb)),        nd3 = LD4(RP(d, hb + 1)),
           nd4 = LD4(RP(d, CH(hb + 2)));
    float4 pm0 = LD4(RP(ld, CH(hb - 1))), pm1 = LD4(RP(ld, hb)), pm2 = LD4(RP(ld, hb + 1));
    float4 pp0 = LD4(RP(hd, CH(hb - 1))), pp1 = LD4(RP(hd, hb)), pp2 = LD4(RP(hd, hb + 1));

#pragma unroll
    for (int s = 0; s < 4; ++s) {
        const int h = hb + s;
        const float4 qp = LD4(RP(dp2, h));
        const float4 qm = LD4(RP(dm2, h));

        int lh, hh; float sh; lohi(h, lh, hh, sh);
        float s_hh, s_lh; lohi(hh, ti, tj, s_hh); lohi(lh, ti, tj, s_lh);
        const bool h_top = (h == 127), h_bot = (h == 0);

        float c_lz = __shfl(nd2.z, lane - 1), c_lw = __shfl(nd2.w, lane - 1);
        float c_rx = __shfl(nd2.x, lane + 1), c_ry = __shfl(nd2.y, lane + 1);
        float r1_lw = __shfl(nd1.w, lane - 1), r1_rx = __shfl(nd1.x, lane + 1);
        float r3_lw = __shfl(nd3.w, lane - 1), r3_rx = __shfl(nd3.x, lane + 1);
        float pmlw = __shfl(pm1.w, lane - 1), pmrx = __shfl(pm1.x, lane + 1);
        float pplw = __shfl(pp1.w, lane - 1), pprx = __shfl(pp1.x, lane + 1);

        const float va[4]  = {nd2.x, nd2.y, nd2.z, nd2.w};
        const float n0a[4] = {nd0.x, nd0.y, nd0.z, nd0.w};
        const float n1a[4] = {nd1.x, nd1.y, nd1.z, nd1.w};
        const float n3a[4] = {nd3.x, nd3.y, nd3.z, nd3.w};
        const float n4a[4] = {nd4.x, nd4.y, nd4.z, nd4.w};
        const float pm0a[4] = {pm0.x, pm0.y, pm0.z, pm0.w};
        const float pm1a[4] = {pm1.x, pm1.y, pm1.z, pm1.w};
        const float pm2a[4] = {pm2.x, pm2.y, pm2.z, pm2.w};
        const float pp0a[4] = {pp0.x, pp0.y, pp0.z, pp0.w};
        const float pp1a[4] = {pp1.x, pp1.y, pp1.z, pp1.w};
        const float pp2a[4] = {pp2.x, pp2.y, pp2.z, pp2.w};
        const float qpa[4] = {qp.x, qp.y, qp.z, qp.w};
        const float qma[4] = {qm.x, qm.y, qm.z, qm.w};

        const float c_m1[4] = {l0 ? va[0] : c_lw, va[0], va[1], va[2]};
        const float c_p1[4] = {va[1], va[2], va[3], l31 ? va[3] : c_rx};
        const float c_m2[4] = {l0 ? va[0] : c_lz, l0 ? va[0] : c_lw, va[0], va[1]};
        const float c_p2[4] = {va[2], va[3], l31 ? va[3] : c_rx, l31 ? va[3] : c_ry};
        const float r1m[4] = {l0 ? n1a[0] : r1_lw, n1a[0], n1a[1], n1a[2]};
        const float r1p[4] = {n1a[1], n1a[2], n1a[3], l31 ? n1a[3] : r1_rx};
        const float r3m[4] = {l0 ? n3a[0] : r3_lw, n3a[0], n3a[1], n3a[2]};
        const float r3p[4] = {n3a[1], n3a[2], n3a[3], l31 ? n3a[3] : r3_rx};
        const float pmm[4] = {l0 ? pm1a[0] : pmlw, pm1a[0], pm1a[1], pm1a[2]};
        const float pmp[4] = {pm1a[1], pm1a[2], pm1a[3], l31 ? pm1a[3] : pmrx};
        const float ppm[4] = {l0 ? pp1a[0] : pplw, pp1a[0], pp1a[1], pp1a[2]};
        const float ppp[4] = {pp1a[1], pp1a[2], pp1a[3], l31 ? pp1a[3] : pprx};

        float ov[4];
#pragma unroll
        for (int j = 0; j < 4; ++j) {
            const float fDD = sd * (s_hd * (qpa[j] - (d_top ? pm1a[j] : va[j]))
                                  - s_ld * ((d_bot ? pp1a[j] : va[j]) - qma[j]));
            const float fHH = sh * (s_hh * (n4a[j] - (h_top ? n1a[j] : va[j]))
                                  - s_lh * ((h_bot ? n3a[j] : va[j]) - n0a[j]));
            const float fDH = sd * sh * ((pp2a[j] - pp0a[j]) - (pm2a[j] - pm0a[j]));
            const float fHW = sh * sw[j] * ((r3p[j] - r3m[j]) - (r1p[j] - r1m[j]));
            const float fDW = sd * sw[j] * ((ppp[j] - ppm[j]) - (pmp[j] - pmm[j]));
            const float Aw = (j == 3 && l31) ? c_m1[j] : va[j];
            const float Bw = (j == 0 && l0) ? c_p1[j] : va[j];
            const float fWW = sw[j] * (s_hw[j] * (c_p2[j] - Aw) - s_lw[j] * (Bw - c_m2[j]));

            const float ft[6] = {fDD, fDH, fDW, fHH, fHW, fWW};
            float o = b2[0];
#pragma unroll
            for (int u = 0; u < 10; ++u) {
                float a = b1e[u];
#pragma unroll
                for (int k = 0; k < 6; ++k) a = fmaf(ft[k], W1[u * 7 + k], a);
                a = fmaxf(a, 0.f);
                o = fmaf(a, W2[u], o);
            }
            float e = __expf(-o);
            ov[j] = __builtin_amdgcn_rcpf(1.0f + e);
        }
        *reinterpret_cast<float4*>(obase + (h << 7)) = make_float4(ov[0], ov[1], ov[2], ov[3]);

        nd0 = nd1; nd1 = nd2; nd2 = nd3; nd3 = nd4;
        nd4 = LD4(RP(d, CH(h + 3)));
        pm0 = pm1; pm1 = pm2; pm2 = LD4(RP(ld, CH(h + 2)));
        pp0 = pp1; pp1 = pp2; pp2 = LD4(RP(hd, CH(h + 2)));
    }
}

// ---------------------------------------------------------------------------
extern "C" void kernel_launch(void* const* d_in, const int* in_sizes, int n_in,
                              void* d_out, int out_size, void* d_ws, size_t ws_size,
                              hipStream_t stream) {
    const float* x     = (const float*)d_in[0];
    const float* scale = (const float*)d_in[1];
    const float* W1    = (const float*)d_in[2];
    const float* b1    = (const float*)d_in[3];
    const float* W2    = (const float*)d_in[4];
    const float* b2    = (const float*)d_in[5];
    float* out = (float*)d_out;

    float* ws0 = (float*)d_ws;            // S volume (16 MB)
    float* ws1 = ws0 + NVOX;              // W+H-blurred volume (16 MB)

    wh_blur_kernel<<<2 * 128 * 4, 256, 0, stream>>>(x, ws1, scale);        // W+H
    dblur_kernel<<<512, 256, 0, stream>>>(ws1, ws0, scale);                // D (LDS-staged)
    hess_mlp_kernel<<<NVOX / 16 / 256, 256, 0, stream>>>(ws0, scale, W1, b1, W2, b2, out);
}

// Round 12
// 44.319 us; speedup vs baseline: 1.0726x; 1.0165x over previous
//
#include <hip/hip_runtime.h>
#include <math.h>

#define NVOX (2 * 128 * 128 * 128)   // 4,194,304
#define KS 13
#define KR 6
#define LROWS 44                      // 32 output rows + 2*6 halo

__device__ __forceinline__ float4 LD4(const float* p) {
    return *reinterpret_cast<const float4*>(p);
}

// Per-thread normalized Gaussian weights (sigma = clip(scale, 0.1, 10)).
__device__ __forceinline__ void make_weights(float scale, float* wv) {
    float sig = fminf(fmaxf(scale, 0.1f), 10.0f);
    float inv2s2 = -1.0f / (2.0f * sig * sig);
    float sum = 0.f;
#pragma unroll
    for (int t = 0; t < KS; ++t) {
        float d = (float)(t - KR);
        wv[t] = __expf(d * d * inv2s2);
        sum += wv[t];
    }
    float r = 1.0f / sum;
#pragma unroll
    for (int t = 0; t < KS; ++t) wv[t] *= r;
}

// ---------------------------------------------------------------------------
// 1) Fused W+H blur, 4 blocks per (b,d) slice (h-quarters + 6-row halo).
//    Phase A: 8 w-outputs per slot, all-vector loads (interior 6x f4,
//    edges 4x f4 + clamp-broadcast). XCD swizzle (nwg=1024).
// ---------------------------------------------------------------------------
__global__ __launch_bounds__(256) void wh_blur_kernel(const float* __restrict__ in,
                                                      float* __restrict__ out,
                                                      const float* __restrict__ scale_p) {
    __shared__ float T[LROWS * 128];      // 22.5 KB
    const int i = blockIdx.x;
    const int wid = ((i & 7) << 7) | (i >> 3);   // bijective, nwg=1024
    const int slice = wid >> 2;           // b*128 + d
    const int h0 = (wid & 3) << 5;        // 0/32/64/96
    const float* sp = in + (slice << 14);
    float* op = out + (slice << 14);

    float wv[KS];
    make_weights(scale_p[0], wv);

    // ---- Phase A: W-blur rows h0-6 .. h0+37 (clamped) into T[0..43] ----
    // 704 slots; slot = (row lr = g>>4, 8-wide w-segment wseg = g&15).
    for (int it = 0; it < 3; ++it) {
        int g = threadIdx.x + (it << 8);
        if (g < LROWS * 16) {
            int wseg = g & 15;
            int w0 = wseg << 3;
            int lr = g >> 4;
            int r = h0 - 6 + lr;
            r = r < 0 ? 0 : (r > 127 ? 127 : r);
            const float* rp = sp + (r << 7);

            float F[24];                  // F[i] = row[w0-8+i]; taps F[k+2..k+14]
            if (wseg >= 1 && wseg <= 14) {
#pragma unroll
                for (int i2 = 0; i2 < 6; ++i2) {
                    float4 q = LD4(rp + w0 - 8 + (i2 << 2));
                    F[4 * i2] = q.x; F[4 * i2 + 1] = q.y;
                    F[4 * i2 + 2] = q.z; F[4 * i2 + 3] = q.w;
                }
            } else if (wseg == 0) {       // w0 = 0: F[0..7] clamp to rp[0]
                float e = rp[0];
#pragma unroll
                for (int i2 = 0; i2 < 8; ++i2) F[i2] = e;
#pragma unroll
                for (int i2 = 0; i2 < 4; ++i2) {
                    float4 q = LD4(rp + (i2 << 2));
                    F[8 + 4 * i2] = q.x; F[9 + 4 * i2] = q.y;
                    F[10 + 4 * i2] = q.z; F[11 + 4 * i2] = q.w;
                }
            } else {                      // wseg = 15, w0 = 120: F[16..23] clamp
                float e = rp[127];
#pragma unroll
                for (int i2 = 0; i2 < 4; ++i2) {
                    float4 q = LD4(rp + 112 + (i2 << 2));
                    F[4 * i2] = q.x; F[4 * i2 + 1] = q.y;
                    F[4 * i2 + 2] = q.z; F[4 * i2 + 3] = q.w;
                }
#pragma unroll
                for (int i2 = 16; i2 < 24; ++i2) F[i2] = e;
            }

            float a[8];
#pragma unroll
            for (int k = 0; k < 8; ++k) a[k] = 0.f;
#pragma unroll
            for (int t = 0; t < KS; ++t) {
                float wt = wv[t];
#pragma unroll
                for (int k = 0; k < 8; ++k) a[k] = fmaf(wt, F[k + 2 + t], a[k]);
            }
            *reinterpret_cast<float4*>(&T[(lr << 7) + w0]) =
                make_float4(a[0], a[1], a[2], a[3]);
            *reinterpret_cast<float4*>(&T[(lr << 7) + w0 + 4]) =
                make_float4(a[4], a[5], a[6], a[7]);
        }
    }
    __syncthreads();

    // ---- Phase B: H-blur 32 output rows (8 strips of 4 rows) ----
    {
        const int w0 = (threadIdx.x & 31) << 2;
        const int r0 = (threadIdx.x >> 5) << 2;

        float4 win[KS];
#pragma unroll
        for (int t = 0; t < KS; ++t) win[t] = LD4(&T[((r0 + t) << 7) + w0]);
#pragma unroll
        for (int s = 0; s < 4; ++s) {
            float4 acc = make_float4(0.f, 0.f, 0.f, 0.f);
#pragma unroll
            for (int t = 0; t < KS; ++t) {
                float4 v = win[(s + t) % KS];
                float wt = wv[t];
                acc.x = fmaf(wt, v.x, acc.x);
                acc.y = fmaf(wt, v.y, acc.y);
                acc.z = fmaf(wt, v.z, acc.z);
                acc.w = fmaf(wt, v.w, acc.w);
            }
            *reinterpret_cast<float4*>(op + ((h0 + r0 + s) << 7) + w0) = acc;
            int nl = r0 + s + 13;
            nl = nl > LROWS - 1 ? LROWS - 1 : nl;   // s=3 load unused, keep in-range
            win[s % KS] = LD4(&T[(nl << 7) + w0]);
        }
    }
}

// ---------------------------------------------------------------------------
// 2) D-blur, register sliding window, d-chunk of 8 (512 blocks).
//    XCD swizzle aligned with wh_blur's d-slabs (nwg=512).
// ---------------------------------------------------------------------------
__global__ __launch_bounds__(256) void dblur_kernel(const float* __restrict__ in,
                                                    float* __restrict__ out,
                                                    const float* __restrict__ scale_p) {
    const int i = blockIdx.x;
    const int wid = ((i & 7) << 6) | (i >> 3);   // bijective, nwg=512
    const int t0 = wid * 256 + threadIdx.x;      // 0..131071
    const int w0 = (t0 & 31) << 2;
    const int h  = (t0 >> 5) & 127;
    const int d0 = ((t0 >> 12) & 15) << 3;       // 16 chunks of 8
    const int b  = t0 >> 16;
    const int base = (b << 21) | (h << 7) | w0;

    float wv[KS];
    make_weights(scale_p[0], wv);

    float4 win[KS];
#pragma unroll
    for (int t = 0; t < KS; ++t) {
        int r = d0 - 6 + t;
        r = r < 0 ? 0 : (r > 127 ? 127 : r);     // d0 max=120 -> d0+6 ok, keep both
        win[t] = LD4(in + base + (r << 14));
    }
#pragma unroll
    for (int s = 0; s < 8; ++s) {
        float4 acc = make_float4(0.f, 0.f, 0.f, 0.f);
#pragma unroll
        for (int t = 0; t < KS; ++t) {
            float4 v = win[(s + t) % KS];
            float wt = wv[t];
            acc.x = fmaf(wt, v.x, acc.x);
            acc.y = fmaf(wt, v.y, acc.y);
            acc.z = fmaf(wt, v.z, acc.z);
            acc.w = fmaf(wt, v.w, acc.w);
        }
        *reinterpret_cast<float4*>(out + base + ((d0 + s) << 14)) = acc;
        int rn = d0 + s + 7;
        rn = rn > 127 ? 127 : rn;
        win[s % KS] = LD4(in + base + (rn << 14));
    }
}

// ---------------------------------------------------------------------------
// 3) Hessian + MLP, h-sliding register window + shuffle w-neighbors,
//    h-chunk of 4 (1024 blocks). scale folded into b1 (launch-constant).
//    XCD swizzle aligned with dblur's d-slabs (nwg=1024). Scalar MLP.
//    (R5 form — measured local optimum; R6/R7/R8 variants all <= it.)
// ---------------------------------------------------------------------------
__device__ __forceinline__ void lohi(int c, int& lo, int& hi, float& s) {
    lo = c > 0 ? c - 1 : 0;
    hi = c < 127 ? c + 1 : 127;
    s = 1.0f / (float)(hi - lo);
}

__device__ __forceinline__ int CH(int v) {
    return v < 0 ? 0 : (v > 127 ? 127 : v);
}

__global__ __launch_bounds__(256) void hess_mlp_kernel(const float* __restrict__ S,
                                const float* __restrict__ scale_p,
                                const float* __restrict__ W1, const float* __restrict__ b1,
                                const float* __restrict__ W2, const float* __restrict__ b2,
                                float* __restrict__ out) {
    const int i = blockIdx.x;
    const int wid = ((i & 7) << 7) | (i >> 3);   // bijective, nwg=1024
    const int t = wid * 256 + threadIdx.x;       // 0..262143
    const int l = t & 31;
    const int w0 = l << 2;
    const int hb = ((t >> 5) & 31) << 2;         // h-strip base (4 rows)
    const int d = (t >> 10) & 127;
    const int b = t >> 17;
    const int lane = threadIdx.x & 63;
    const bool l0 = (l == 0), l31 = (l == 31);

    int ld, hd; float sd; lohi(d, ld, hd, sd);
    int ti, tj; float s_hd, s_ld;
    lohi(hd, ti, tj, s_hd); lohi(ld, ti, tj, s_ld);
    const bool d_top = (d == 127), d_bot = (d == 0);
    const int dp2 = d > 125 ? 127 : d + 2;
    const int dm2 = d < 2 ? 0 : d - 2;

    float sw[4], s_hw[4], s_lw[4];
#pragma unroll
    for (int j = 0; j < 4; ++j) {
        int lw, hw; lohi(w0 + j, lw, hw, sw[j]);
        lohi(hw, ti, tj, s_hw[j]); lohi(lw, ti, tj, s_lw[j]);
    }

    const float scale = scale_p[0];
    // Fold the constant 7th feature (scale) into the bias: saves 10 FMA/voxel.
    float b1e[10];
#pragma unroll
    for (int u = 0; u < 10; ++u) b1e[u] = fmaf(scale, W1[u * 7 + 6], b1[u]);

    const float* base = S + (b << 21) + w0;
    auto RP = [&](int dd, int hh) { return base + (dd << 14) + (hh << 7); };
    float* obase = out + (b << 21) + (d << 14) + w0;

    float4 nd0 = LD4(RP(d, CH(hb - 2))), nd1 = LD4(RP(d, CH(hb - 1))),
           nd2 = LD4(RP(d, hb)),        nd3 = LD4(RP(d, hb + 1)),
           nd4 = LD4(RP(d, CH(hb + 2)));
    float4 pm0 = LD4(RP(ld, CH(hb - 1))), pm1 = LD4(RP(ld, hb)), pm2 = LD4(RP(ld, hb + 1));
    float4 pp0 = LD4(RP(hd, CH(hb - 1))), pp1 = LD4(RP(hd, hb)), pp2 = LD4(RP(hd, hb + 1));

#pragma unroll
    for (int s = 0; s < 4; ++s) {
        const int h = hb + s;
        const float4 qp = LD4(RP(dp2, h));
        const float4 qm = LD4(RP(dm2, h));

        int lh, hh; float sh; lohi(h, lh, hh, sh);
        float s_hh, s_lh; lohi(hh, ti, tj, s_hh); lohi(lh, ti, tj, s_lh);
        const bool h_top = (h == 127), h_bot = (h == 0);

        float c_lz = __shfl(nd2.z, lane - 1), c_lw = __shfl(nd2.w, lane - 1);
        float c_rx = __shfl(nd2.x, lane + 1), c_ry = __shfl(nd2.y, lane + 1);
        float r1_lw = __shfl(nd1.w, lane - 1), r1_rx = __shfl(nd1.x, lane + 1);
        float r3_lw = __shfl(nd3.w, lane - 1), r3_rx = __shfl(nd3.x, lane + 1);
        float pmlw = __shfl(pm1.w, lane - 1), pmrx = __shfl(pm1.x, lane + 1);
        float pplw = __shfl(pp1.w, lane - 1), pprx = __shfl(pp1.x, lane + 1);

        const float va[4]  = {nd2.x, nd2.y, nd2.z, nd2.w};
        const float n0a[4] = {nd0.x, nd0.y, nd0.z, nd0.w};
        const float n1a[4] = {nd1.x, nd1.y, nd1.z, nd1.w};
        const float n3a[4] = {nd3.x, nd3.y, nd3.z, nd3.w};
        const float n4a[4] = {nd4.x, nd4.y, nd4.z, nd4.w};
        const float pm0a[4] = {pm0.x, pm0.y, pm0.z, pm0.w};
        const float pm1a[4] = {pm1.x, pm1.y, pm1.z, pm1.w};
        const float pm2a[4] = {pm2.x, pm2.y, pm2.z, pm2.w};
        const float pp0a[4] = {pp0.x, pp0.y, pp0.z, pp0.w};
        const float pp1a[4] = {pp1.x, pp1.y, pp1.z, pp1.w};
        const float pp2a[4] = {pp2.x, pp2.y, pp2.z, pp2.w};
        const float qpa[4] = {qp.x, qp.y, qp.z, qp.w};
        const float qma[4] = {qm.x, qm.y, qm.z, qm.w};

        const float c_m1[4] = {l0 ? va[0] : c_lw, va[0], va[1], va[2]};
        const float c_p1[4] = {va[1], va[2], va[3], l31 ? va[3] : c_rx};
        const float c_m2[4] = {l0 ? va[0] : c_lz, l0 ? va[0] : c_lw, va[0], va[1]};
        const float c_p2[4] = {va[2], va[3], l31 ? va[3] : c_rx, l31 ? va[3] : c_ry};
        const float r1m[4] = {l0 ? n1a[0] : r1_lw, n1a[0], n1a[1], n1a[2]};
        const float r1p[4] = {n1a[1], n1a[2], n1a[3], l31 ? n1a[3] : r1_rx};
        const float r3m[4] = {l0 ? n3a[0] : r3_lw, n3a[0], n3a[1], n3a[2]};
        const float r3p[4] = {n3a[1], n3a[2], n3a[3], l31 ? n3a[3] : r3_rx};
        const float pmm[4] = {l0 ? pm1a[0] : pmlw, pm1a[0], pm1a[1], pm1a[2]};
        const float pmp[4] = {pm1a[1], pm1a[2], pm1a[3], l31 ? pm1a[3] : pmrx};
        const float ppm[4] = {l0 ? pp1a[0] : pplw, pp1a[0], pp1a[1], pp1a[2]};
        const float ppp[4] = {pp1a[1], pp1a[2], pp1a[3], l31 ? pp1a[3] : pprx};

        float ov[4];
#pragma unroll
        for (int j = 0; j < 4; ++j) {
            const float fDD = sd * (s_hd * (qpa[j] - (d_top ? pm1a[j] : va[j]))
                                  - s_ld * ((d_bot ? pp1a[j] : va[j]) - qma[j]));
            const float fHH = sh * (s_hh * (n4a[j] - (h_top ? n1a[j] : va[j]))
                                  - s_lh * ((h_bot ? n3a[j] : va[j]) - n0a[j]));
            const float fDH = sd * sh * ((pp2a[j] - pp0a[j]) - (pm2a[j] - pm0a[j]));
            const float fHW = sh * sw[j] * ((r3p[j] - r3m[j]) - (r1p[j] - r1m[j]));
            const float fDW = sd * sw[j] * ((ppp[j] - ppm[j]) - (pmp[j] - pmm[j]));
            const float Aw = (j == 3 && l31) ? c_m1[j] : va[j];
            const float Bw = (j == 0 && l0) ? c_p1[j] : va[j];
            const float fWW = sw[j] * (s_hw[j] * (c_p2[j] - Aw) - s_lw[j] * (Bw - c_m2[j]));

            const float ft[6] = {fDD, fDH, fDW, fHH, fHW, fWW};
            float o = b2[0];
#pragma unroll
            for (int u = 0; u < 10; ++u) {
                float a = b1e[u];
#pragma unroll
                for (int k = 0; k < 6; ++k) a = fmaf(ft[k], W1[u * 7 + k], a);
                a = fmaxf(a, 0.f);
                o = fmaf(a, W2[u], o);
            }
            float e = __expf(-o);
            ov[j] = __builtin_amdgcn_rcpf(1.0f + e);
        }
        *reinterpret_cast<float4*>(obase + (h << 7)) = make_float4(ov[0], ov[1], ov[2], ov[3]);

        nd0 = nd1; nd1 = nd2; nd2 = nd3; nd3 = nd4;
        nd4 = LD4(RP(d, CH(h + 3)));
        pm0 = pm1; pm1 = pm2; pm2 = LD4(RP(ld, CH(h + 2)));
        pp0 = pp1; pp1 = pp2; pp2 = LD4(RP(hd, CH(h + 2)));
    }
}

// ---------------------------------------------------------------------------
extern "C" void kernel_launch(void* const* d_in, const int* in_sizes, int n_in,
                              void* d_out, int out_size, void* d_ws, size_t ws_size,
                              hipStream_t stream) {
    const float* x     = (const float*)d_in[0];
    const float* scale = (const float*)d_in[1];
    const float* W1    = (const float*)d_in[2];
    const float* b1    = (const float*)d_in[3];
    const float* W2    = (const float*)d_in[4];
    const float* b2    = (const float*)d_in[5];
    float* out = (float*)d_out;

    float* ws0 = (float*)d_ws;            // S volume (16 MB)
    float* ws1 = ws0 + NVOX;              // W+H-blurred volume (16 MB)

    wh_blur_kernel<<<2 * 128 * 4, 256, 0, stream>>>(x, ws1, scale);        // W+H
    dblur_kernel<<<NVOX / 32 / 256, 256, 0, stream>>>(ws1, ws0, scale);    // D (chunk 8)
    hess_mlp_kernel<<<NVOX / 16 / 256, 256, 0, stream>>>(ws0, scale, W1, b1, W2, b2, out);
}